// Round 15
// baseline (429.004 us; speedup 1.0000x reference)
//
#include <hip/hip_runtime.h>
#include <math.h>

#define T_STEPS 1024
#define B_SIZE  512
#define D_IN    225
#define WT_K    228
#define LOG2E   1.4426950408889634f

typedef float f32x2 __attribute__((ext_vector_type(2)));

__device__ __forceinline__ float fexp2(float x) {
#if __has_builtin(__builtin_amdgcn_exp2f)
  return __builtin_amdgcn_exp2f(x);
#else
  return exp2f(x);
#endif
}
__device__ __forceinline__ float frcp(float x) {
#if __has_builtin(__builtin_amdgcn_rcpf)
  return __builtin_amdgcn_rcpf(x);
#else
  return 1.0f / x;
#endif
}
#define SIG(x) frcp(1.0f + fexp2((x) * (-LOG2E)))
#define TH(x)  fmaf(2.0f, frcp(1.0f + fexp2((x) * (-2.0f * LOG2E))), -1.0f)

#define GL16(gp, lp) __builtin_amdgcn_global_load_lds(                          \
    (const __attribute__((address_space(1))) void*)(gp),                        \
    (__attribute__((address_space(3))) void*)(lp), 16, 0, 0)
#define GL4(gp, lp)  __builtin_amdgcn_global_load_lds(                          \
    (const __attribute__((address_space(1))) void*)(gp),                        \
    (__attribute__((address_space(3))) void*)(lp), 4, 0, 0)

#define WAIT_VM0() do {                                                         \
    asm volatile("s_waitcnt vmcnt(0)" ::: "memory");                            \
    __builtin_amdgcn_sched_barrier(0);                                          \
  } while (0)
#define WAIT_VM10() do {                                                        \
    asm volatile("s_waitcnt vmcnt(10)" ::: "memory");                           \
    __builtin_amdgcn_sched_barrier(0);                                          \
  } while (0)
// barrier that does NOT drain vmcnt: wait only to the given count first
#define BARRIER_VM(N) do {                                                      \
    asm volatile("s_waitcnt vmcnt(" #N ")\n\ts_barrier" ::: "memory");          \
    __builtin_amdgcn_sched_barrier(0);                                          \
  } while (0)

// -------- Kernel 0: wt2[g*228+k] = Wih[g*225+k] (pad 0); bias at 4560 -------
__global__ __launch_bounds__(256)
void prep_wt(const float* __restrict__ Wih, const float* __restrict__ bih,
             const float* __restrict__ bhh, float* __restrict__ wt2)
{
  int i = blockIdx.x * 256 + threadIdx.x;      // 0..4607
  int g = i / WT_K, kk = i - g * WT_K;
  float v = 0.f;
  if (g < 20 && kk < 225) v = Wih[g * 225 + kk];
  if (i >= 4560 && i < 4580) v = bih[i - 4560] + bhh[i - 4560];
  wt2[i] = v;
}

// -------- Kernel 1: xg' (permuted) = x @ Wih0^T + b, persistent ping-pong ---
// 512 persistent blocks x 256 thr; 16 tiles of 64 rows each. W staged once.
// Per tile: issue B -> compute A -> [vmcnt(0);barrier] -> issue A(t+1)
// -> compute B -> stores -> [vmcnt(5);barrier]. Steady-state staging is
// fully hidden under compute. Raw barriers keep prefetch loads in flight.
// A: k<112 at LDS stride 116 fl (swizzled src, 32 chunks = 8/wave);
// B: k 112..223 at stride 112 fl (28 chunks = 7/wave); k224 column via GL4.
__global__ __launch_bounds__(256)
void xg_gemm(const float* __restrict__ x, const float* __restrict__ wtg,
             float* __restrict__ xg)
{
  __shared__ __align__(16) float xsA[8192];       // 32768 B (64 rows x 116 + pad)
  __shared__ __align__(16) float xsB[7168];       // 28672 B (64 rows x 112)
  __shared__ __align__(16) float wt[4608];        // 18432 B
  __shared__ float xs224[64];                     // 256 B   (tot 80128 -> 2/CU)
  const int tid  = threadIdx.x;
  const int lane = tid & 63;
  const int w    = __builtin_amdgcn_readfirstlane(tid >> 6);   // 0..3 uniform

  const int tile0 = blockIdx.x * 16;

#define ISSUE_A(TI)                                                            \
  { const uint32_t base_ = (uint32_t)(TI) * 57600u;                            \
    _Pragma("unroll")                                                          \
    for (int i_ = 0; i_ < 8; ++i_) {                                           \
      int m_ = w * 8 + i_;                                                     \
      uint32_t c_ = (uint32_t)(m_ * 64 + lane);                                \
      c_ = (c_ > 1855u) ? 1855u : c_;            /* dup chunks clamp in-tile */\
      uint32_t r_ = __umulhi(c_, 148102321u);    /* c / 29 */                  \
      uint32_t q_ = c_ - 29u * r_;                                             \
      GL16((const char*)x + base_ + r_ * 900u + q_ * 16u,                      \
           (char*)xsA + m_ * 1024);                                            \
    } }

#define ISSUE_B(TI)                                                            \
  { const uint32_t base_ = (uint32_t)(TI) * 57600u;                            \
    _Pragma("unroll")                                                          \
    for (int i_ = 0; i_ < 7; ++i_) {                                           \
      int m_ = w * 7 + i_;                                                     \
      uint32_t c_ = (uint32_t)(m_ * 64 + lane);                                \
      uint32_t r_ = __umulhi(c_, 153391690u);    /* c / 28 */                  \
      uint32_t q_ = c_ - 28u * r_;                                             \
      GL16((const char*)x + base_ + r_ * 900u + 448u + q_ * 16u,               \
           (char*)xsB + m_ * 1024);                                            \
    }                                                                          \
    GL4(x + (size_t)(TI) * 14400 + lane * 225 + 224, xs224 + lane); }

  // prologue: W (once) + A(tile0); full drain
  for (int m = w; m < 18; m += 4)
    GL16(wtg + m * 256 + lane * 4, wt + m * 256);
  ISSUE_A(tile0)
  WAIT_VM0();
  __builtin_amdgcn_s_barrier();

  const float* wr = wt + (5 * w) * WT_K;          // wave-uniform -> broadcast

  for (int t = 0; t < 16; ++t) {
    const int tile = tile0 + t;
    ISSUE_B(tile)                                  // 8 loads/wave, in flight

    float acc[5];
#pragma unroll
    for (int j = 0; j < 5; ++j) acc[j] = wt[4560 + 5 * w + j];

    // compute A-half: k = 0..111 (B staging underneath)
    {
      const float* xr = xsA + lane * 116;
#pragma unroll 7
      for (int kb = 0; kb < 112; kb += 4) {
        const float4 xv = *(const float4*)(xr + kb);
#pragma unroll
        for (int j = 0; j < 5; ++j) {
          const float4 wv = *(const float4*)(wr + j * WT_K + kb);
          acc[j] = fmaf(xv.x, wv.x, acc[j]);
          acc[j] = fmaf(xv.y, wv.y, acc[j]);
          acc[j] = fmaf(xv.z, wv.z, acc[j]);
          acc[j] = fmaf(xv.w, wv.w, acc[j]);
        }
      }
    }
    BARRIER_VM(0);                                 // B ready; A buffer free

    if (t < 15) ISSUE_A(tile + 1)                  // 8 loads/wave, in flight

    // compute B-half: k = 112..224 (A(t+1) staging underneath)
    {
      const float* xr = xsB + lane * 112;
#pragma unroll 7
      for (int kb = 0; kb < 112; kb += 4) {
        const float4 xv = *(const float4*)(xr + kb);
#pragma unroll
        for (int j = 0; j < 5; ++j) {
          const float4 wv = *(const float4*)(wr + j * WT_K + 112 + kb);
          acc[j] = fmaf(xv.x, wv.x, acc[j]);
          acc[j] = fmaf(xv.y, wv.y, acc[j]);
          acc[j] = fmaf(xv.z, wv.z, acc[j]);
          acc[j] = fmaf(xv.w, wv.w, acc[j]);
        }
      }
      float xl = xs224[lane];
#pragma unroll
      for (int j = 0; j < 5; ++j) acc[j] = fmaf(xl, wr[j * WT_K + 224], acc[j]);
    }
    // permuted store: gate (5w+j) -> slot 4*j + w
    float* op = xg + ((size_t)tile * 64 + lane) * 20 + w;
#pragma unroll
    for (int j = 0; j < 5; ++j) op[4 * j] = acc[j];

    BARRIER_VM(5);                                 // A(t+1) landed; stores fly
  }
#undef ISSUE_A
#undef ISSUE_B
}

// -------- Kernel 2: 6-stage pipeline in one half-wave (round-9/12 best) -----
__global__ __launch_bounds__(64)
void lstm_fused(const float* __restrict__ xg, float* __restrict__ out,
              const float* __restrict__ l1_Whh0,
              const float* __restrict__ l1_Wih1, const float* __restrict__ l1_Whh1,
              const float* __restrict__ l1_bih1, const float* __restrict__ l1_bhh1,
              const float* __restrict__ fc1_W,  const float* __restrict__ fc1_b,
              const float* __restrict__ l2_Wih0, const float* __restrict__ l2_Whh0,
              const float* __restrict__ l2_bih0, const float* __restrict__ l2_bhh0,
              const float* __restrict__ l2_Wih1, const float* __restrict__ l2_Whh1,
              const float* __restrict__ l2_bih1, const float* __restrict__ l2_bhh1,
              const float* __restrict__ fc2_W,  const float* __restrict__ fc2_b)
{
  __shared__ __align__(16) float xq[2][2][1280];   // [buf][elem][64t*20] 20480 B
  __shared__ float outb[2][64][5];                 // 2560 B
  const int lane  = threadIdx.x & 63;
  const int half  = lane >> 5;
  const int l32   = lane & 31;
  const int stage = (l32 < 30) ? (l32 / 5) : 6;
  const int u     = (l32 < 30) ? (l32 - stage * 5) : 0;
  const int b0    = blockIdx.x * 2;

  const bool is_l0   = (stage == 0);
  const bool is_relu = (stage == 2);
  const bool is_fc   = (stage == 2) || (stage == 5);
  const bool is_fc2  = (stage == 5);

  float wi[4][5] = {}, wh[4][5] = {}, bs[4] = {};
  if (stage == 0) {
#pragma unroll
    for (int q = 0; q < 4; ++q)
#pragma unroll
      for (int j = 0; j < 5; ++j) wh[q][j] = l1_Whh0[(u + 5 * q) * 5 + j];
  } else if (stage == 1) {
#pragma unroll
    for (int q = 0; q < 4; ++q) {
#pragma unroll
      for (int j = 0; j < 5; ++j) {
        wi[q][j] = l1_Wih1[(u + 5 * q) * 5 + j];
        wh[q][j] = l1_Whh1[(u + 5 * q) * 5 + j];
      }
      bs[q] = l1_bih1[u + 5 * q] + l1_bhh1[u + 5 * q];
    }
  } else if (stage == 3) {
#pragma unroll
    for (int q = 0; q < 4; ++q) {
#pragma unroll
      for (int j = 0; j < 5; ++j) {
        wi[q][j] = l2_Wih0[(u + 5 * q) * 5 + j];
        wh[q][j] = l2_Whh0[(u + 5 * q) * 5 + j];
      }
      bs[q] = l2_bih0[u + 5 * q] + l2_bhh0[u + 5 * q];
    }
  } else if (stage == 4) {
#pragma unroll
    for (int q = 0; q < 4; ++q) {
#pragma unroll
      for (int j = 0; j < 5; ++j) {
        wi[q][j] = l2_Wih1[(u + 5 * q) * 5 + j];
        wh[q][j] = l2_Whh1[(u + 5 * q) * 5 + j];
      }
      bs[q] = l2_bih1[u + 5 * q] + l2_bhh1[u + 5 * q];
    }
  } else if (stage == 2) {      // FC1: a-chain = fc1_W . in + fc1_b (wh = 0)
#pragma unroll
    for (int j = 0; j < 5; ++j) wi[0][j] = fc1_W[u * 5 + j];
    bs[0] = fc1_b[u];
  } else if (stage == 5) {      // FC2: a-chain = fc2_W . in + fc2_b
#pragma unroll
    for (int j = 0; j < 5; ++j) wi[0][j] = fc2_W[u * 5 + j];
    bs[0] = fc2_b[u];
  }

  // pack gate pairs (0,1) and (2,3) for v_pk_fma_f32
  f32x2 wi01[5], wi23[5], wh01[5], wh23[5];
#pragma unroll
  for (int j = 0; j < 5; ++j) {
    wi01[j] = f32x2{wi[0][j], wi[1][j]};
    wi23[j] = f32x2{wi[2][j], wi[3][j]};
    wh01[j] = f32x2{wh[0][j], wh[1][j]};
    wh23[j] = f32x2{wh[2][j], wh[3][j]};
  }
  const f32x2 bs01 = f32x2{bs[0], bs[1]};
  const f32x2 bs23 = f32x2{bs[2], bs[3]};

  // bpermute byte-indices (loop-invariant). in <- prev stage's lanes, hh <- own.
  int ii[5], ih[5];
  const int bse = half * 32;
  const int inb = (stage >= 1 && stage <= 5) ? (stage - 1) * 5 : 0;
  const int hb_ = (stage <= 5) ? stage * 5 : 0;
#pragma unroll
  for (int j = 0; j < 5; ++j) {
    ii[j] = (bse + inb + j) * 4;
    ih[j] = (bse + hb_ + j) * 4;
  }

  // FLUSH constants (per lane, loop-invariant): each thread drains 10 slots.
  const float* obf = &outb[0][0][0];
  float* outbase = out + (size_t)b0 * T_STEPS * 5;
  int lof[10], ofs[10];
  bool fg1[10], fg2[10];
#pragma unroll
  for (int i2 = 0; i2 < 10; ++i2) {
    int idx = i2 * 64 + lane;
    int e  = (idx >= 320) ? 1 : 0;
    int r  = idx - e * 320;
    int tq = r / 5;
    int j2 = r - tq * 5;
    lof[i2] = e * 320 + (((tq - 5) & 63) * 5) + j2;   // outb read (chunk-invar)
    ofs[i2] = e * (T_STEPS * 5) + tq * 5 + j2;        // out store base offset
    fg1[i2] = (tq >= 5);                              // first chunk: tt >= 0
    fg2[i2] = (tq < 5);                               // last flush: tt < T
  }

  const float* src0 = xg + (size_t)(b0 + 0) * T_STEPS * 20;
  const float* src1 = xg + (size_t)(b0 + 1) * T_STEPS * 20;

#define STAGE_CHUNK(CH, BUF)                                                   \
  { const float* s0_ = src0 + (CH) * 1280;                                     \
    const float* s1_ = src1 + (CH) * 1280;                                     \
    float* d0_ = &xq[BUF][0][0];                                               \
    float* d1_ = &xq[BUF][1][0];                                               \
    _Pragma("unroll")                                                          \
    for (int m = 0; m < 5; ++m) {                                              \
      GL16(s0_ + m * 256 + lane * 4, d0_ + m * 256);                           \
      GL16(s1_ + m * 256 + lane * 4, d1_ + m * 256);                           \
    } }

// One tick. QV is a pre-loaded float4 register (no LDS read on the chain).
#define TICK(QV, GUARDED, KVAL)                                                \
  { const int hvi_ = __float_as_int(hv);                                       \
    float inx[5], hhx[5];                                                      \
    _Pragma("unroll")                                                          \
    for (int j = 0; j < 5; ++j) {                                              \
      inx[j] = __int_as_float(__builtin_amdgcn_ds_bpermute(ii[j], hvi_));      \
      hhx[j] = __int_as_float(__builtin_amdgcn_ds_bpermute(ih[j], hvi_));      \
    }                                                                          \
    f32x2 a01 = is_l0 ? f32x2{(QV).x, (QV).y} : bs01;                          \
    f32x2 a23 = is_l0 ? f32x2{(QV).z, (QV).w} : bs23;                          \
    f32x2 b01, b23;                                                            \
    { const f32x2 h0 = f32x2{hhx[0], hhx[0]};                                  \
      b01 = wh01[0] * h0; b23 = wh23[0] * h0; }                                \
    _Pragma("unroll")                                                          \
    for (int j = 0; j < 5; ++j) {                                              \
      const f32x2 xj = f32x2{inx[j], inx[j]};                                  \
      a01 = __builtin_elementwise_fma(wi01[j], xj, a01);                       \
      a23 = __builtin_elementwise_fma(wi23[j], xj, a23);                       \
    }                                                                          \
    _Pragma("unroll")                                                          \
    for (int j = 1; j < 5; ++j) {                                              \
      const f32x2 hj = f32x2{hhx[j], hhx[j]};                                  \
      b01 = __builtin_elementwise_fma(wh01[j], hj, b01);                       \
      b23 = __builtin_elementwise_fma(wh23[j], hj, b23);                       \
    }                                                                          \
    const f32x2 pre01 = a01 + b01, pre23 = a23 + b23;                          \
    float i_ = SIG(pre01.x), f_ = SIG(pre01.y);                                \
    float g_ = TH(pre23.x),  o_ = SIG(pre23.y);                                \
    float cn = fmaf(f_, c, i_ * g_);                                           \
    float hl = o_ * TH(cn);                                                    \
    float fx = is_relu ? fmaxf(pre01.x, 0.0f) : i_;                            \
    float hn = is_fc ? fx : hl;                                                \
    if (GUARDED) { bool ok = (KVAL) >= stage; c = ok ? cn : c; hv = ok ? hn : hv; } \
    else         { c = cn; hv = hn; }                                          \
    if (is_fc2) outb[half][((KVAL) + 59) & 63][u] = i_;                        \
  }

#define LQ(T) (*(const float4*)(xqb + 20 * (T)))
#define MINQ(X) (((X) > 63) ? 63 : (X))

// 64 ticks with 4-deep register Q prefetch (reload clamped within chunk)
#define CHUNK_BODY(GUARDED)                                                    \
  { float4 qA = LQ(0), qB = LQ(1), qC = LQ(2), qD = LQ(3);                     \
    _Pragma("unroll")                                                          \
    for (int g4 = 0; g4 < 16; ++g4) {                                          \
      const int kk = g4 * 4;                                                   \
      TICK(qA, GUARDED, kk + 0)                                                \
      qA = LQ(MINQ(kk + 4));                                                   \
      TICK(qB, GUARDED, kk + 1)                                                \
      qB = LQ(MINQ(kk + 5));                                                   \
      TICK(qC, GUARDED, kk + 2)                                                \
      qC = LQ(MINQ(kk + 6));                                                   \
      TICK(qD, GUARDED, kk + 3)                                                \
      qD = LQ(MINQ(kk + 7));                                                   \
    } }

// MODE: 0 = no guard (middle), 1 = first chunk, 2 = final drain
#define FLUSH(TBASE, MODE)                                                     \
  { _Pragma("unroll")                                                          \
    for (int i2 = 0; i2 < 10; ++i2) {                                          \
      float v = obf[lof[i2]];                                                  \
      bool ok = (MODE == 0) || ((MODE == 1) ? fg1[i2] : fg2[i2]);              \
      if (ok) outbase[ofs[i2] + (TBASE) * 5] = v;                              \
    } }

  float hv = 0.f, c = 0.f;

  STAGE_CHUNK(0, 0)
  WAIT_VM0();

  { // chunk 0: guarded ticks (pipeline fill)
    STAGE_CHUNK(1, 1)
    const float* xqb = &xq[0][half][4 * u];
    CHUNK_BODY(true)
    FLUSH(-5, 1)
    WAIT_VM10();   // 10 loads (chunk 1) + 10 stores outstanding -> drains loads
  }
  for (int ch = 1; ch < 16; ++ch) {
    if (ch < 15) STAGE_CHUNK(ch + 1, (ch + 1) & 1)
    const float* xqb = &xq[ch & 1][half][4 * u];
    CHUNK_BODY(false)
    FLUSH(ch * 64 - 5, 0)
    WAIT_VM10();
  }
  { // drain: 5 ticks; stale Q values unused downstream of t >= T
    const float* xqb = &xq[0][half][4 * u];
    float4 qZ = LQ(0);
    TICK(qZ, false, 0)
    TICK(qZ, false, 1)
    TICK(qZ, false, 2)
    TICK(qZ, false, 3)
    TICK(qZ, false, 4)
    FLUSH(T_STEPS - 5, 2)
  }

#undef STAGE_CHUNK
#undef TICK
#undef LQ
#undef MINQ
#undef CHUNK_BODY
#undef FLUSH
}

// ---------------------------------------------------------------------------
extern "C" void kernel_launch(void* const* d_in, const int* in_sizes, int n_in,
                              void* d_out, int out_size, void* d_ws, size_t ws_size,
                              hipStream_t stream)
{
  const float* x        = (const float*)d_in[0];
  const float* l1_Wih0  = (const float*)d_in[1];
  const float* l1_Whh0  = (const float*)d_in[2];
  const float* l1_bih0  = (const float*)d_in[3];
  const float* l1_bhh0  = (const float*)d_in[4];
  const float* l1_Wih1  = (const float*)d_in[5];
  const float* l1_Whh1  = (const float*)d_in[6];
  const float* l1_bih1  = (const float*)d_in[7];
  const float* l1_bhh1  = (const float*)d_in[8];
  const float* fc1_W    = (const float*)d_in[9];
  const float* fc1_b    = (const float*)d_in[10];
  const float* l2_Wih0  = (const float*)d_in[11];
  const float* l2_Whh0  = (const float*)d_in[12];
  const float* l2_bih0  = (const float*)d_in[13];
  const float* l2_bhh0  = (const float*)d_in[14];
  const float* l2_Wih1  = (const float*)d_in[15];
  const float* l2_Whh1  = (const float*)d_in[16];
  const float* l2_bih1  = (const float*)d_in[17];
  const float* l2_bhh1  = (const float*)d_in[18];
  const float* fc2_W    = (const float*)d_in[19];
  const float* fc2_b    = (const float*)d_in[20];

  float* xg   = (float*)d_ws;                  // 10,485,760 floats
  float* wtws = xg + 10485760;                 // 4,608 floats (W_T + bias)
  float* out  = (float*)d_out;

  prep_wt<<<dim3(18), dim3(256), 0, stream>>>(l1_Wih0, l1_bih0, l1_bhh0, wtws);

  xg_gemm<<<dim3(512), dim3(256), 0, stream>>>(x, wtws, xg);

  lstm_fused<<<dim3(B_SIZE / 2), dim3(64), 0, stream>>>(
      xg, out, l1_Whh0, l1_Wih1, l1_Whh1, l1_bih1, l1_bhh1,
      fc1_W, fc1_b, l2_Wih0, l2_Whh0, l2_bih0, l2_bhh0,
      l2_Wih1, l2_Whh1, l2_bih1, l2_bhh1, fc2_W, fc2_b);
}

// Round 16
// 350.505 us; speedup vs baseline: 1.2240x; 1.2240x over previous
//
#include <hip/hip_runtime.h>
#include <math.h>

#define T_STEPS 1024
#define B_SIZE  512
#define D_IN    225
#define LOG2E   1.4426950408889634f

typedef float f32x2 __attribute__((ext_vector_type(2)));

__device__ __forceinline__ float fexp2(float x) {
#if __has_builtin(__builtin_amdgcn_exp2f)
  return __builtin_amdgcn_exp2f(x);
#else
  return exp2f(x);
#endif
}
__device__ __forceinline__ float frcp(float x) {
#if __has_builtin(__builtin_amdgcn_rcpf)
  return __builtin_amdgcn_rcpf(x);
#else
  return 1.0f / x;
#endif
}
#define SIG(x) frcp(1.0f + fexp2((x) * (-LOG2E)))
#define TH(x)  fmaf(2.0f, frcp(1.0f + fexp2((x) * (-2.0f * LOG2E))), -1.0f)

#define GL16(gp, lp) __builtin_amdgcn_global_load_lds(                          \
    (const __attribute__((address_space(1))) void*)(gp),                        \
    (__attribute__((address_space(3))) void*)(lp), 16, 0, 0)
#define GL4(gp, lp)  __builtin_amdgcn_global_load_lds(                          \
    (const __attribute__((address_space(1))) void*)(gp),                        \
    (__attribute__((address_space(3))) void*)(lp), 4, 0, 0)

#define WAIT_VM0() do {                                                         \
    asm volatile("s_waitcnt vmcnt(0)" ::: "memory");                            \
    __builtin_amdgcn_sched_barrier(0);                                          \
  } while (0)

// -------- Kernel 0: k-major W for layer0: wt2[k*20+g]; bias at 4500 ---------
__global__ __launch_bounds__(256)
void prep_wt(const float* __restrict__ Wih, const float* __restrict__ bih,
             const float* __restrict__ bhh, float* __restrict__ wt2)
{
  int i = blockIdx.x * 256 + threadIdx.x;      // 0..4607
  float v = 0.f;
  if (i < 4500) {
    int k = i / 20, g = i - k * 20;
    v = Wih[g * D_IN + k];
  } else if (i < 4520) {
    v = bih[i - 4500] + bhh[i - 4500];
  }
  wt2[i] = v;
}

// -------- Fused kernel: wave0 = 6-stage LSTM pipeline (r14 structure);
// waves 1-2 = xg producers computing layer-0 input pre-activations for the
// NEXT 64-tick chunk directly into the xq LDS double buffer (no xg HBM
// round-trip, no separate GEMM kernel). One __syncthreads per chunk.
__global__ __launch_bounds__(256)
void lstm_fused(const float* __restrict__ x, const float* __restrict__ wtg,
              float* __restrict__ out,
              const float* __restrict__ l1_Whh0,
              const float* __restrict__ l1_Wih1, const float* __restrict__ l1_Whh1,
              const float* __restrict__ l1_bih1, const float* __restrict__ l1_bhh1,
              const float* __restrict__ fc1_W,  const float* __restrict__ fc1_b,
              const float* __restrict__ l2_Wih0, const float* __restrict__ l2_Whh0,
              const float* __restrict__ l2_bih0, const float* __restrict__ l2_bhh0,
              const float* __restrict__ l2_Wih1, const float* __restrict__ l2_Whh1,
              const float* __restrict__ l2_bih1, const float* __restrict__ l2_bhh1,
              const float* __restrict__ fc2_W,  const float* __restrict__ fc2_b)
{
  __shared__ __align__(16) float xq[2][2][1280];   // [buf][elem][64t*20] 20480 B
  __shared__ __align__(16) float xsl[2][14400];    // x slabs (2 elem)  115200 B
  __shared__ __align__(16) float wt[4608];         // k-major W + bias   18432 B
  __shared__ float outb[2][64][5];                 //                     2560 B
  const int tid   = threadIdx.x;                   // total 156672 B -> 1 blk/CU
  const int lane  = tid & 63;
  const int wv    = tid >> 6;                      // 0 = consumer, 1-2 producers
  const int half  = lane >> 5;
  const int l32   = lane & 31;
  const int stage = (l32 < 30) ? (l32 / 5) : 6;
  const int u     = (l32 < 30) ? (l32 - stage * 5) : 0;
  const int b0    = blockIdx.x * 2;

  const bool is_l0   = (stage == 0);
  const bool is_relu = (stage == 2);
  const bool is_fc   = (stage == 2) || (stage == 5);
  const bool is_fc2  = (stage == 5);

  float wi[4][5] = {}, wh[4][5] = {}, bs[4] = {};
  if (stage == 0) {
#pragma unroll
    for (int q = 0; q < 4; ++q)
#pragma unroll
      for (int j = 0; j < 5; ++j) wh[q][j] = l1_Whh0[(u + 5 * q) * 5 + j];
  } else if (stage == 1) {
#pragma unroll
    for (int q = 0; q < 4; ++q) {
#pragma unroll
      for (int j = 0; j < 5; ++j) {
        wi[q][j] = l1_Wih1[(u + 5 * q) * 5 + j];
        wh[q][j] = l1_Whh1[(u + 5 * q) * 5 + j];
      }
      bs[q] = l1_bih1[u + 5 * q] + l1_bhh1[u + 5 * q];
    }
  } else if (stage == 3) {
#pragma unroll
    for (int q = 0; q < 4; ++q) {
#pragma unroll
      for (int j = 0; j < 5; ++j) {
        wi[q][j] = l2_Wih0[(u + 5 * q) * 5 + j];
        wh[q][j] = l2_Whh0[(u + 5 * q) * 5 + j];
      }
      bs[q] = l2_bih0[u + 5 * q] + l2_bhh0[u + 5 * q];
    }
  } else if (stage == 4) {
#pragma unroll
    for (int q = 0; q < 4; ++q) {
#pragma unroll
      for (int j = 0; j < 5; ++j) {
        wi[q][j] = l2_Wih1[(u + 5 * q) * 5 + j];
        wh[q][j] = l2_Whh1[(u + 5 * q) * 5 + j];
      }
      bs[q] = l2_bih1[u + 5 * q] + l2_bhh1[u + 5 * q];
    }
  } else if (stage == 2) {      // FC1: a-chain = fc1_W . in + fc1_b (wh = 0)
#pragma unroll
    for (int j = 0; j < 5; ++j) wi[0][j] = fc1_W[u * 5 + j];
    bs[0] = fc1_b[u];
  } else if (stage == 5) {      // FC2: a-chain = fc2_W . in + fc2_b
#pragma unroll
    for (int j = 0; j < 5; ++j) wi[0][j] = fc2_W[u * 5 + j];
    bs[0] = fc2_b[u];
  }

  // pack gate pairs (0,1) and (2,3) for v_pk_fma_f32
  f32x2 wi01[5], wi23[5], wh01[5], wh23[5];
#pragma unroll
  for (int j = 0; j < 5; ++j) {
    wi01[j] = f32x2{wi[0][j], wi[1][j]};
    wi23[j] = f32x2{wi[2][j], wi[3][j]};
    wh01[j] = f32x2{wh[0][j], wh[1][j]};
    wh23[j] = f32x2{wh[2][j], wh[3][j]};
  }
  const f32x2 bs01 = f32x2{bs[0], bs[1]};
  const f32x2 bs23 = f32x2{bs[2], bs[3]};

  // bpermute byte-indices (loop-invariant). in <- prev stage's lanes, hh <- own.
  int ii[5], ih[5];
  const int bse = half * 32;
  const int inb = (stage >= 1 && stage <= 5) ? (stage - 1) * 5 : 0;
  const int hb_ = (stage <= 5) ? stage * 5 : 0;
#pragma unroll
  for (int j = 0; j < 5; ++j) {
    ii[j] = (bse + inb + j) * 4;
    ih[j] = (bse + hb_ + j) * 4;
  }

  // FLUSH constants (wave0 only uses them)
  const float* obf = &outb[0][0][0];
  float* outbase = out + (size_t)b0 * T_STEPS * 5;
  int lof[10], ofs[10];
  bool fg1[10], fg2[10];
#pragma unroll
  for (int i2 = 0; i2 < 10; ++i2) {
    int idx = i2 * 64 + lane;
    int e  = (idx >= 320) ? 1 : 0;
    int r  = idx - e * 320;
    int tq = r / 5;
    int j2 = r - tq * 5;
    lof[i2] = e * 320 + (((tq - 5) & 63) * 5) + j2;   // outb read (chunk-invar)
    ofs[i2] = e * (T_STEPS * 5) + tq * 5 + j2;        // out store base offset
    fg1[i2] = (tq >= 5);                              // first chunk: tt >= 0
    fg2[i2] = (tq < 5);                               // last flush: tt < T
  }

// ---------------- producer: stage slab + compute 64 rows of xg' -------------
#define AG(G) (((G) & 1) ? acc2[(G) >> 1].y : acc2[(G) >> 1].x)
#define PRODUCE(CH, BUF)                                                       \
  { const int e_ = wv - 1;                                                     \
    const float* slab_ = x + ((size_t)(b0 + e_) * T_STEPS + (CH) * 64) * 225;  \
    float* dst_ = &xsl[e_][0];                                                 \
    _Pragma("unroll")                                                          \
    for (int m_ = 0; m_ < 56; ++m_)                                            \
      GL16(slab_ + m_ * 256 + lane * 4, dst_ + m_ * 256);                      \
    GL4(slab_ + 14336 + lane, dst_ + 14336);                                   \
    WAIT_VM0();                                                                \
    f32x2 acc2[10];                                                            \
    _Pragma("unroll")                                                          \
    for (int p_ = 0; p_ < 10; ++p_)                                            \
      acc2[p_] = f32x2{wt[4500 + 2 * p_], wt[4500 + 2 * p_ + 1]};              \
    const float* xr_ = dst_ + lane * 225;                                      \
    _Pragma("unroll 3")                                                        \
    for (int k_ = 0; k_ < 225; ++k_) {                                         \
      const float xv_ = xr_[k_];                                               \
      const f32x2 xv2_ = f32x2{xv_, xv_};                                      \
      const float* wk_ = wt + k_ * 20;                                         \
      const float4 wA_ = *(const float4*)(wk_);                                \
      const float4 wB_ = *(const float4*)(wk_ + 4);                            \
      const float4 wC_ = *(const float4*)(wk_ + 8);                            \
      const float4 wD_ = *(const float4*)(wk_ + 12);                           \
      const float4 wE_ = *(const float4*)(wk_ + 16);                           \
      acc2[0] = __builtin_elementwise_fma(f32x2{wA_.x, wA_.y}, xv2_, acc2[0]); \
      acc2[1] = __builtin_elementwise_fma(f32x2{wA_.z, wA_.w}, xv2_, acc2[1]); \
      acc2[2] = __builtin_elementwise_fma(f32x2{wB_.x, wB_.y}, xv2_, acc2[2]); \
      acc2[3] = __builtin_elementwise_fma(f32x2{wB_.z, wB_.w}, xv2_, acc2[3]); \
      acc2[4] = __builtin_elementwise_fma(f32x2{wC_.x, wC_.y}, xv2_, acc2[4]); \
      acc2[5] = __builtin_elementwise_fma(f32x2{wC_.z, wC_.w}, xv2_, acc2[5]); \
      acc2[6] = __builtin_elementwise_fma(f32x2{wD_.x, wD_.y}, xv2_, acc2[6]); \
      acc2[7] = __builtin_elementwise_fma(f32x2{wD_.z, wD_.w}, xv2_, acc2[7]); \
      acc2[8] = __builtin_elementwise_fma(f32x2{wE_.x, wE_.y}, xv2_, acc2[8]); \
      acc2[9] = __builtin_elementwise_fma(f32x2{wE_.z, wE_.w}, xv2_, acc2[9]); \
    }                                                                          \
    float* qp_ = &xq[BUF][e_][lane * 20];                                      \
    _Pragma("unroll")                                                          \
    for (int u_ = 0; u_ < 5; ++u_) {                                           \
      float4 o_;                                                               \
      o_.x = AG(u_);      o_.y = AG(5 + u_);                                   \
      o_.z = AG(10 + u_); o_.w = AG(15 + u_);                                  \
      *(float4*)(qp_ + 4 * u_) = o_;                                           \
    } }

// ---------------- consumer tick (identical to round-14 best) ----------------
#define TICK(QV, GUARDED, KVAL)                                                \
  { const int hvi_ = __float_as_int(hv);                                       \
    float inx[5], hhx[5];                                                      \
    _Pragma("unroll")                                                          \
    for (int j = 0; j < 5; ++j) {                                              \
      inx[j] = __int_as_float(__builtin_amdgcn_ds_bpermute(ii[j], hvi_));      \
      hhx[j] = __int_as_float(__builtin_amdgcn_ds_bpermute(ih[j], hvi_));      \
    }                                                                          \
    f32x2 a01 = is_l0 ? f32x2{(QV).x, (QV).y} : bs01;                          \
    f32x2 a23 = is_l0 ? f32x2{(QV).z, (QV).w} : bs23;                          \
    f32x2 b01, b23;                                                            \
    { const f32x2 h0 = f32x2{hhx[0], hhx[0]};                                  \
      b01 = wh01[0] * h0; b23 = wh23[0] * h0; }                                \
    _Pragma("unroll")                                                          \
    for (int j = 0; j < 5; ++j) {                                              \
      const f32x2 xj = f32x2{inx[j], inx[j]};                                  \
      a01 = __builtin_elementwise_fma(wi01[j], xj, a01);                       \
      a23 = __builtin_elementwise_fma(wi23[j], xj, a23);                       \
    }                                                                          \
    _Pragma("unroll")                                                          \
    for (int j = 1; j < 5; ++j) {                                              \
      const f32x2 hj = f32x2{hhx[j], hhx[j]};                                  \
      b01 = __builtin_elementwise_fma(wh01[j], hj, b01);                       \
      b23 = __builtin_elementwise_fma(wh23[j], hj, b23);                       \
    }                                                                          \
    const f32x2 pre01 = a01 + b01, pre23 = a23 + b23;                          \
    float i_ = SIG(pre01.x), f_ = SIG(pre01.y);                                \
    float g_ = TH(pre23.x),  o_ = SIG(pre23.y);                                \
    float cn = fmaf(f_, c, i_ * g_);                                           \
    float hl = o_ * TH(cn);                                                    \
    float fx = is_relu ? fmaxf(pre01.x, 0.0f) : i_;                            \
    float hn = is_fc ? fx : hl;                                                \
    if (GUARDED) { bool ok = (KVAL) >= stage; c = ok ? cn : c; hv = ok ? hn : hv; } \
    else         { c = cn; hv = hn; }                                          \
    if (is_fc2) outb[half][((KVAL) + 59) & 63][u] = i_;                        \
  }

#define LQ(T) (*(const float4*)(xqb + 20 * (T)))
#define MINQ(X) (((X) > 63) ? 63 : (X))

#define CHUNK_BODY(GUARDED)                                                    \
  { float4 qA = LQ(0), qB = LQ(1), qC = LQ(2), qD = LQ(3);                     \
    _Pragma("unroll")                                                          \
    for (int g4 = 0; g4 < 16; ++g4) {                                          \
      const int kk = g4 * 4;                                                   \
      TICK(qA, GUARDED, kk + 0)                                                \
      qA = LQ(MINQ(kk + 4));                                                   \
      TICK(qB, GUARDED, kk + 1)                                                \
      qB = LQ(MINQ(kk + 5));                                                   \
      TICK(qC, GUARDED, kk + 2)                                                \
      qC = LQ(MINQ(kk + 6));                                                   \
      TICK(qD, GUARDED, kk + 3)                                                \
      qD = LQ(MINQ(kk + 7));                                                   \
    } }

#define FLUSH(TBASE, MODE)                                                     \
  { _Pragma("unroll")                                                          \
    for (int i2 = 0; i2 < 10; ++i2) {                                          \
      float v = obf[lof[i2]];                                                  \
      bool ok = (MODE == 0) || ((MODE == 1) ? fg1[i2] : fg2[i2]);              \
      if (ok) outbase[ofs[i2] + (TBASE) * 5] = v;                              \
    } }

  float hv = 0.f, c = 0.f;

  // prologue: producers stage W (k-major) then produce chunk 0 into buf 0
  if (wv == 1 || wv == 2) {
    for (int m = wv - 1; m < 18; m += 2)
      GL16(wtg + m * 256 + lane * 4, wt + m * 256);
    WAIT_VM0();
  }
  __syncthreads();                    // W visible to both producers
  if (wv == 1 || wv == 2) PRODUCE(0, 0)
  __syncthreads();                    // chunk 0 ready

  for (int ch = 0; ch < 16; ++ch) {
    if (wv == 0) {
      const float* xqb = &xq[ch & 1][half][4 * u];
      if (ch == 0) {
        CHUNK_BODY(true)
        FLUSH(-5, 1)
      } else {
        CHUNK_BODY(false)
        FLUSH(ch * 64 - 5, 0)
      }
    } else if ((wv == 1 || wv == 2) && ch < 15) {
      PRODUCE(ch + 1, (ch + 1) & 1)
    }
    __syncthreads();
  }
  if (wv == 0) {  // drain: 5 ticks; stale Q values unused downstream of t >= T
    const float* xqb = &xq[0][half][4 * u];
    float4 qZ = LQ(0);
    TICK(qZ, false, 0)
    TICK(qZ, false, 1)
    TICK(qZ, false, 2)
    TICK(qZ, false, 3)
    TICK(qZ, false, 4)
    FLUSH(T_STEPS - 5, 2)
  }

#undef AG
#undef PRODUCE
#undef TICK
#undef LQ
#undef MINQ
#undef CHUNK_BODY
#undef FLUSH
}

// ---------------------------------------------------------------------------
extern "C" void kernel_launch(void* const* d_in, const int* in_sizes, int n_in,
                              void* d_out, int out_size, void* d_ws, size_t ws_size,
                              hipStream_t stream)
{
  const float* x        = (const float*)d_in[0];
  const float* l1_Wih0  = (const float*)d_in[1];
  const float* l1_Whh0  = (const float*)d_in[2];
  const float* l1_bih0  = (const float*)d_in[3];
  const float* l1_bhh0  = (const float*)d_in[4];
  const float* l1_Wih1  = (const float*)d_in[5];
  const float* l1_Whh1  = (const float*)d_in[6];
  const float* l1_bih1  = (const float*)d_in[7];
  const float* l1_bhh1  = (const float*)d_in[8];
  const float* fc1_W    = (const float*)d_in[9];
  const float* fc1_b    = (const float*)d_in[10];
  const float* l2_Wih0  = (const float*)d_in[11];
  const float* l2_Whh0  = (const float*)d_in[12];
  const float* l2_bih0  = (const float*)d_in[13];
  const float* l2_bhh0  = (const float*)d_in[14];
  const float* l2_Wih1  = (const float*)d_in[15];
  const float* l2_Whh1  = (const float*)d_in[16];
  const float* l2_bih1  = (const float*)d_in[17];
  const float* l2_bhh1  = (const float*)d_in[18];
  const float* fc2_W    = (const float*)d_in[19];
  const float* fc2_b    = (const float*)d_in[20];

  float* wtws = (float*)d_ws;                  // 4,608 floats (k-major W + bias)
  float* out  = (float*)d_out;

  prep_wt<<<dim3(18), dim3(256), 0, stream>>>(l1_Wih0, l1_bih0, l1_bhh0, wtws);

  lstm_fused<<<dim3(B_SIZE / 2), dim3(256), 0, stream>>>(
      x, wtws, out, l1_Whh0, l1_Wih1, l1_Whh1, l1_bih1, l1_bhh1,
      fc1_W, fc1_b, l2_Wih0, l2_Whh0, l2_bih0, l2_bhh0,
      l2_Wih1, l2_Whh1, l2_bih1, l2_bhh1, fc2_W, fc2_b);
}